// Round 5
// baseline (201.184 us; speedup 1.0000x reference)
//
#include <hip/hip_runtime.h>

#define NB 16
#define NCIN 256
#define NL 2048
#define NHID 512
#define NM 512
#define NLP 1024

typedef short bf16x8 __attribute__((ext_vector_type(8)));
typedef unsigned short u16x8 __attribute__((ext_vector_type(8)));
typedef float f32x4 __attribute__((ext_vector_type(4)));
typedef __attribute__((address_space(1))) const unsigned int gas_u32;
typedef __attribute__((address_space(3))) unsigned int las_u32;

__device__ __forceinline__ unsigned short f2bf(float f) {
    unsigned int u = __builtin_bit_cast(unsigned int, f);
    return (unsigned short)((u + 0x7FFFu + ((u >> 16) & 1u)) >> 16);
}
__device__ __forceinline__ float bf2f(unsigned short u) {
    return __builtin_bit_cast(float, ((unsigned int)u) << 16);
}

// ================ k_front: conv1x1+bias+relu+pool direct from x (bb<512),
//                  plus P cast/transpose (512..639) and wT transpose (640..895)
__global__ __launch_bounds__(512) void k_front(
    const float* __restrict__ x, const float* __restrict__ w1,
    const float* __restrict__ b1, const float* __restrict__ P,
    const float* __restrict__ wT, unsigned short* __restrict__ hb,
    unsigned short* __restrict__ Pb, unsigned short* __restrict__ Ptb,
    unsigned short* __restrict__ wTt)
{
    __shared__ __align__(16) unsigned short smem[66560];  // 133,120 B
    const int bb = blockIdx.x;
    const int t = threadIdx.x;

    if (bb >= 512) {
        if (bb < 640) {   // P -> Pb (cast) and Ptb (transpose), 64x64 tiles
            unsigned short (*tbuf)[65] = (unsigned short (*)[65])smem;
            const int pb = bb - 512;
            const int mt = pb >> 4, lt = pb & 15;
            for (int i = t; i < 4096; i += 512) {
                const int r = i >> 6, c = i & 63;
                const unsigned short v = f2bf(P[(size_t)(mt * 64 + r) * 1024 + lt * 64 + c]);
                Pb[(size_t)(mt * 64 + r) * 1024 + lt * 64 + c] = v;
                tbuf[c][r] = v;
            }
            __syncthreads();
            for (int i = t; i < 4096; i += 512) {
                const int r = i >> 6, c = i & 63;
                Ptb[(size_t)(lt * 64 + r) * 512 + mt * 64 + c] = tbuf[r][c];
            }
        } else {          // wT -> wTt [g][(o,kk)][i]
            const int t5 = (bb - 640) * 512 + t;   // < 131072
            const int g = t5 >> 16, ok = (t5 >> 8) & 255, i = t5 & 255;
            wTt[t5] = f2bf(wT[(size_t)(g * 256 + i) * 256 + ok]);
        }
        return;
    }

    // ---- conv block: rows r0..r0+127 over (b,l), cols = 256 o of group g
    const int g  = bb & 1;
    const int rt = bb >> 1;
    const int r0 = rt * 128;
    const int b  = r0 >> 11, l0 = r0 & 2047;

    unsigned short* T   = smem;           // [128][136] bf16 (ch, l)
    unsigned short* Asl = smem + 17408;   // [128][128] bf16 (l, ch)
    unsigned short* Bsl = smem + 33792;   // [256][128] bf16 (o, ch)
    unsigned short* epi = smem;           // [256][72]  (reused after MFMA)

    // load x fp32 -> T bf16 [ch][l]
    #pragma unroll
    for (int i3 = 0; i3 < 8; ++i3) {
        const int idx = i3 * 512 + t;
        const int ch = idx >> 5, f4 = idx & 31;
        const float4 v = *(const float4*)(x + ((size_t)(b * 256 + g * 128 + ch)) * 2048 + l0 + f4 * 4);
        ushort4 u;
        u.x = f2bf(v.x); u.y = f2bf(v.y); u.z = f2bf(v.z); u.w = f2bf(v.w);
        *(ushort4*)(T + ch * 136 + f4 * 4) = u;
    }
    // load w1 fp32 -> Bsl bf16 [o][ch]
    #pragma unroll
    for (int i5 = 0; i5 < 16; ++i5) {
        const int idx = i5 * 512 + t;
        const int o = idx >> 5, f4 = idx & 31;
        const float4 v = *(const float4*)(w1 + ((size_t)(g * 256 + o)) * 128 + f4 * 4);
        ushort4 u;
        u.x = f2bf(v.x); u.y = f2bf(v.y); u.z = f2bf(v.z); u.w = f2bf(v.w);
        *(ushort4*)(Bsl + o * 128 + f4 * 4) = u;
    }
    __syncthreads();
    // transpose T[ch][l] -> Asl[l][ch]; tasks: (ch = idx&127, lo = idx>>7)
    #pragma unroll
    for (int i4 = 0; i4 < 4; ++i4) {
        const int idx = i4 * 512 + t;
        const int ch = idx & 127, lo = idx >> 7;
        const u16x8 v = *(const u16x8*)(T + ch * 136 + lo * 8);
        #pragma unroll
        for (int u2 = 0; u2 < 8; ++u2)
            Asl[(lo * 8 + u2) * 128 + ch] = v[u2];
    }
    __syncthreads();

    const int lane = t & 63, wave = t >> 6;
    const int wm = wave & 1, wn = wave >> 1;      // 2 x 4 waves, tile 64x64
    const int q = lane >> 4, lm = lane & 15;

    f32x4 acc[4][4];
    #pragma unroll
    for (int i = 0; i < 4; ++i)
        #pragma unroll
        for (int j = 0; j < 4; ++j)
            #pragma unroll
            for (int r = 0; r < 4; ++r) acc[i][j][r] = 0.f;

    #pragma unroll
    for (int kc = 0; kc < 4; ++kc) {   // K=128 = 4 x 32
        bf16x8 af[4], bf[4];
        #pragma unroll
        for (int i = 0; i < 4; ++i)
            af[i] = *(const bf16x8*)(Asl + (wm * 64 + i * 16 + lm) * 128 + kc * 32 + q * 8);
        #pragma unroll
        for (int j = 0; j < 4; ++j)
            bf[j] = *(const bf16x8*)(Bsl + (wn * 64 + j * 16 + lm) * 128 + kc * 32 + q * 8);
        #pragma unroll
        for (int i = 0; i < 4; ++i)
            #pragma unroll
            for (int j = 0; j < 4; ++j)
                acc[i][j] = __builtin_amdgcn_mfma_f32_16x16x32_bf16(af[i], bf[j], acc[i][j], 0, 0, 0);
    }
    __syncthreads();   // Asl/Bsl/T dead; epi reuses region

    // epilogue: pool adjacent l (regs r pairs) + bias + relu -> epi[o][lp]
    #pragma unroll
    for (int j = 0; j < 4; ++j) {
        const int col = wn * 64 + j * 16 + lm;            // o local [0,256)
        const float bias = b1[g * 256 + col];
        #pragma unroll
        for (int i = 0; i < 4; ++i) {
            const float p0 = fmaxf(fmaxf(acc[i][j][0], acc[i][j][1]) + bias, 0.f);
            const float p1 = fmaxf(fmaxf(acc[i][j][2], acc[i][j][3]) + bias, 0.f);
            const int lp_loc = wm * 32 + i * 8 + q * 2;   // [0,64)
            ushort2 u; u.x = f2bf(p0); u.y = f2bf(p1);
            *(ushort2*)(epi + col * 72 + lp_loc) = u;
        }
    }
    __syncthreads();
    const int c_loc = t >> 1, half = t & 1;
    unsigned short* dst = hb + ((size_t)(b * 512 + g * 256 + c_loc)) * 1024 + (l0 >> 1) + half * 32;
    #pragma unroll
    for (int u = 0; u < 4; ++u)
        *(u16x8*)(dst + u * 8) = *(const u16x8*)(epi + c_loc * 72 + half * 32 + u * 8);
}

// ================ k_hop: fused scores + softmax + retrieval
// block = 32 rows of (b,c); phase1 S[32,512]=hb.Pb^T -> LDS; softmax; phase2 h2T = attn.Ptb^T
__global__ __launch_bounds__(512) void k_hop(
    const unsigned short* __restrict__ hb, const unsigned short* __restrict__ Pb,
    const unsigned short* __restrict__ Ptb, unsigned short* __restrict__ h2T)
{
    __shared__ __align__(16) unsigned short smem[51712];  // 103,424 B
    unsigned short* Sbuf = smem;              // [32][528]
    unsigned short* Asl  = smem + 16896;      // phase1 A [32][64]
    unsigned short* Bsl  = smem + 16896 + 2048; // phase1 B [512][64]
    unsigned short* Bsl2 = smem + 16896;      // phase2 B [256][128]

    const int t = threadIdx.x;
    const int r0 = blockIdx.x * 32;           // row over (b,c)
    const int b = r0 >> 9, c0 = r0 & 511;
    const int lane = t & 63, wave = t >> 6;
    const int q = lane >> 4, lm = lane & 15;

    // ---------- phase 1: S = hb_rows . Pb^T   (wave tile 32 rows x 64 cols)
    f32x4 acc1[2][4];
    #pragma unroll
    for (int i = 0; i < 2; ++i)
        #pragma unroll
        for (int j = 0; j < 4; ++j)
            #pragma unroll
            for (int r = 0; r < 4; ++r) acc1[i][j][r] = 0.f;

    for (int kc0 = 0; kc0 < 1024; kc0 += 64) {
        if (t < 256) {    // stage A: 32x64
            const int e = t * 8;
            const int row = e >> 6, col = e & 63;
            const unsigned short* ga = hb + (size_t)(r0 + row) * 1024 + kc0 + col;
            __builtin_amdgcn_global_load_lds((gas_u32*)ga, (las_u32*)(Asl + e), 16, 0, 0);
        }
        #pragma unroll
        for (int i2 = 0; i2 < 8; ++i2) {   // stage B: 512x64
            const int e = (i2 * 512 + t) * 8;
            const int row = e >> 6, col = e & 63;
            const unsigned short* gb = Pb + (size_t)row * 1024 + kc0 + col;
            __builtin_amdgcn_global_load_lds((gas_u32*)gb, (las_u32*)(Bsl + e), 16, 0, 0);
        }
        __syncthreads();
        #pragma unroll
        for (int kk = 0; kk < 2; ++kk) {
            bf16x8 af[2], bf[4];
            #pragma unroll
            for (int i = 0; i < 2; ++i)
                af[i] = *(const bf16x8*)(Asl + (i * 16 + lm) * 64 + kk * 32 + q * 8);
            #pragma unroll
            for (int j = 0; j < 4; ++j)
                bf[j] = *(const bf16x8*)(Bsl + (wave * 64 + j * 16 + lm) * 64 + kk * 32 + q * 8);
            #pragma unroll
            for (int i = 0; i < 2; ++i)
                #pragma unroll
                for (int j = 0; j < 4; ++j)
                    acc1[i][j] = __builtin_amdgcn_mfma_f32_16x16x32_bf16(af[i], bf[j], acc1[i][j], 0, 0, 0);
        }
        __syncthreads();
    }

    // S -> Sbuf bf16 (row = c-local, col = m), padded stride 528
    #pragma unroll
    for (int i = 0; i < 2; ++i)
        #pragma unroll
        for (int j = 0; j < 4; ++j)
            #pragma unroll
            for (int r = 0; r < 4; ++r)
                Sbuf[(i * 16 + q * 4 + r) * 528 + wave * 64 + j * 16 + lm] = f2bf(acc1[i][j][r]);
    __syncthreads();

    // ---------- softmax over m=512 per row; 16 threads/row, 32 cols each
    {
        const int rw = t >> 4, sl = t & 15;
        u16x8 sv[4];
        #pragma unroll
        for (int u = 0; u < 4; ++u)
            sv[u] = *(const u16x8*)(Sbuf + rw * 528 + sl * 32 + u * 8);
        float mx = -3.0e38f;
        #pragma unroll
        for (int u = 0; u < 4; ++u)
            #pragma unroll
            for (int j = 0; j < 8; ++j) mx = fmaxf(mx, bf2f(sv[u][j]));
        #pragma unroll
        for (int off = 1; off < 16; off <<= 1) mx = fmaxf(mx, __shfl_xor(mx, off));
        float vv[32];
        float sum = 0.f;
        #pragma unroll
        for (int u = 0; u < 4; ++u)
            #pragma unroll
            for (int j = 0; j < 8; ++j) {
                const float e = __expf(bf2f(sv[u][j]) - mx);
                vv[u * 8 + j] = e; sum += e;
            }
        #pragma unroll
        for (int off = 1; off < 16; off <<= 1) sum += __shfl_xor(sum, off);
        const float inv = 1.f / sum;
        #pragma unroll
        for (int u = 0; u < 4; ++u) {
            u16x8 ov;
            #pragma unroll
            for (int j = 0; j < 8; ++j) ov[j] = f2bf(vv[u * 8 + j] * inv);
            *(u16x8*)(Sbuf + rw * 528 + sl * 32 + u * 8) = ov;
        }
    }
    __syncthreads();

    // ---------- phase 2: h2 = attn . Ptb^T  (wave tile 32 rows x 32 cols; 4 lp-chunks of 256)
    bf16x8 a[2][16];   // A fragments preloaded: rows 32, K=512
    #pragma unroll
    for (int i = 0; i < 2; ++i)
        #pragma unroll
        for (int kx = 0; kx < 16; ++kx)
            a[i][kx] = *(const bf16x8*)(Sbuf + (i * 16 + lm) * 528 + kx * 32 + q * 8);

    for (int lpc = 0; lpc < 4; ++lpc) {
        const int lp0c = lpc * 256;
        f32x4 acc2[2][2];
        #pragma unroll
        for (int i = 0; i < 2; ++i)
            #pragma unroll
            for (int j = 0; j < 2; ++j)
                #pragma unroll
                for (int r = 0; r < 4; ++r) acc2[i][j][r] = 0.f;

        for (int kc0 = 0; kc0 < 4; ++kc0) {    // m-chunks of 128
            #pragma unroll
            for (int i2 = 0; i2 < 8; ++i2) {   // stage B: 256 lp x 128 m
                const int e = (i2 * 512 + t) * 8;
                const int row = e >> 7, col = e & 127;
                const unsigned short* gb = Ptb + (size_t)(lp0c + row) * 512 + kc0 * 128 + col;
                __builtin_amdgcn_global_load_lds((gas_u32*)gb, (las_u32*)(Bsl2 + e), 16, 0, 0);
            }
            __syncthreads();
            #pragma unroll
            for (int kk = 0; kk < 4; ++kk) {
                const int kx = kc0 * 4 + kk;
                bf16x8 bf2[2];
                #pragma unroll
                for (int j = 0; j < 2; ++j)
                    bf2[j] = *(const bf16x8*)(Bsl2 + (wave * 32 + j * 16 + lm) * 128 + kk * 32 + q * 8);
                #pragma unroll
                for (int i = 0; i < 2; ++i)
                    #pragma unroll
                    for (int j = 0; j < 2; ++j)
                        acc2[i][j] = __builtin_amdgcn_mfma_f32_16x16x32_bf16(a[i][kx], bf2[j], acc2[i][j], 0, 0, 0);
            }
            __syncthreads();
        }
        // store chunk: rows = c, cols = lp; h2T[b][lp][c]
        #pragma unroll
        for (int i = 0; i < 2; ++i)
            #pragma unroll
            for (int j = 0; j < 2; ++j) {
                const int lp = lp0c + wave * 32 + j * 16 + lm;
                ushort4 u;
                u.x = f2bf(acc2[i][j][0]); u.y = f2bf(acc2[i][j][1]);
                u.z = f2bf(acc2[i][j][2]); u.w = f2bf(acc2[i][j][3]);
                *(ushort4*)(h2T + ((size_t)b * 1024 + lp) * 512 + c0 + i * 16 + q * 4) = u;
            }
    }
}

// ================ k4_gemm: convT via MFMA + fused bias/relu/residual (unchanged)
__global__ __launch_bounds__(256) void k4_gemm(
    const unsigned short* __restrict__ h2T, const unsigned short* __restrict__ wTt,
    const float* __restrict__ bT, const float* __restrict__ x,
    const float* __restrict__ RZ, float* __restrict__ out)
{
    const int nt = blockIdx.x & 1;
    const int g  = (blockIdx.x >> 1) & 1;
    const int rt = blockIdx.x >> 2;
    const int r0 = rt * 128;
    const int b  = r0 >> 10, lp0 = r0 & 1023;

    __shared__ __align__(16) char smem[65536];
    unsigned short* Asl = (unsigned short*)smem;
    unsigned short* Bsl = Asl + 128 * 64;
    float* epi = (float*)smem;

    const int t = threadIdx.x;
    const int lane = t & 63;
    const int wave = t >> 6;
    const int wm = wave & 1, wn = wave >> 1;
    const int q = lane >> 4, lm = lane & 15;

    f32x4 acc[4][4];
    #pragma unroll
    for (int i = 0; i < 4; ++i)
        #pragma unroll
        for (int j = 0; j < 4; ++j)
            #pragma unroll
            for (int r = 0; r < 4; ++r) acc[i][j][r] = 0.f;

    for (int k0 = 0; k0 < 256; k0 += 64) {
        #pragma unroll
        for (int rd = 0; rd < 4; ++rd) {
            const int e = rd * 2048 + t * 8;
            const int row = e >> 6, col = e & 63;
            const unsigned short* ga = h2T + (size_t)(r0 + row) * 512 + g * 256 + k0 + col;
            __builtin_amdgcn_global_load_lds((gas_u32*)ga, (las_u32*)(Asl + e), 16, 0, 0);
            const unsigned short* gb = wTt + (size_t)g * 65536 + (size_t)(nt * 128 + row) * 256 + k0 + col;
            __builtin_amdgcn_global_load_lds((gas_u32*)gb, (las_u32*)(Bsl + e), 16, 0, 0);
        }
        __syncthreads();
        #pragma unroll
        for (int kk = 0; kk < 2; ++kk) {
            bf16x8 af[4], bf[4];
            #pragma unroll
            for (int i = 0; i < 4; ++i)
                af[i] = *(const bf16x8*)(Asl + (wm * 64 + i * 16 + lm) * 64 + kk * 32 + q * 8);
            #pragma unroll
            for (int j = 0; j < 4; ++j)
                bf[j] = *(const bf16x8*)(Bsl + (wn * 64 + j * 16 + lm) * 64 + kk * 32 + q * 8);
            #pragma unroll
            for (int i = 0; i < 4; ++i)
                #pragma unroll
                for (int j = 0; j < 4; ++j)
                    acc[i][j] = __builtin_amdgcn_mfma_f32_16x16x32_bf16(af[i], bf[j], acc[i][j], 0, 0, 0);
        }
        __syncthreads();
    }

    #pragma unroll
    for (int j = 0; j < 4; ++j) {
        const int col_blk = wn * 64 + j * 16 + lm;
        const int o_l = col_blk >> 1, kk2 = col_blk & 1;
        #pragma unroll
        for (int i = 0; i < 4; ++i) {
            #pragma unroll
            for (int r = 0; r < 4; ++r) {
                const int row_l = wm * 64 + i * 16 + q * 4 + r;
                const int l_l = 2 * row_l + kk2;
                const int chunk = ((l_l >> 2) + o_l) & 63;
                epi[o_l * 256 + chunk * 4 + (l_l & 3)] = acc[i][j][r];
            }
        }
    }
    __syncthreads();
    const int row = t >> 2, quad = t & 3;
    const int c = g * 128 + nt * 64 + row;
    const float bias = bT[c];
    const float rz = RZ[0];
    const size_t gbase = ((size_t)(b * 256 + c)) * 2048 + 2 * lp0 + quad * 64;
    #pragma unroll
    for (int k = 0; k < 16; ++k) {
        const int chunk_phys = (quad * 16 + k + row) & 63;
        const float4 v = *(const float4*)(epi + row * 256 + chunk_phys * 4);
        const float4 xv = *(const float4*)(x + gbase + k * 4);
        float4 o;
        o.x = xv.x + rz * fmaxf(v.x + bias, 0.f);
        o.y = xv.y + rz * fmaxf(v.y + bias, 0.f);
        o.z = xv.z + rz * fmaxf(v.z + bias, 0.f);
        o.w = xv.w + rz * fmaxf(v.w + bias, 0.f);
        *(float4*)(out + gbase + k * 4) = o;
    }
}

extern "C" void kernel_launch(void* const* d_in, const int* in_sizes, int n_in,
                              void* d_out, int out_size, void* d_ws, size_t ws_size,
                              hipStream_t stream) {
    (void)in_sizes; (void)n_in; (void)out_size; (void)ws_size;
    const float* x  = (const float*)d_in[0];
    const float* w1 = (const float*)d_in[1];
    const float* b1 = (const float*)d_in[2];
    const float* P  = (const float*)d_in[3];
    const float* wT = (const float*)d_in[4];
    const float* bT = (const float*)d_in[5];
    const float* RZ = (const float*)d_in[6];
    float* out = (float*)d_out;

    // workspace (34.25 MB):
    //   [0,16M)   hb  bf16 [8192,1024]
    //   [16,32M)  h2T bf16 [16,1024,512]
    //   [32,33M)  Pb bf16 [512,1024]; [33,34M) Ptb bf16 [1024,512]; [34M..) wTt 256K
    char* ws = (char*)d_ws;
    unsigned short* hb  = (unsigned short*)ws;
    unsigned short* h2T = (unsigned short*)(ws + (16u << 20));
    unsigned short* Pb  = (unsigned short*)(ws + (32u << 20));
    unsigned short* Ptb = (unsigned short*)(ws + (33u << 20));
    unsigned short* wTt = (unsigned short*)(ws + (34u << 20));

    hipLaunchKernelGGL(k_front, dim3(896), dim3(512), 0, stream,
                       x, w1, b1, P, wT, hb, Pb, Ptb, wTt);
    hipLaunchKernelGGL(k_hop,   dim3(256), dim3(512), 0, stream, hb, Pb, Ptb, h2T);
    hipLaunchKernelGGL(k4_gemm, dim3(512), dim3(256), 0, stream, h2T, wTt, bT, x, RZ, out);
}